// Round 1
// baseline (1024.876 us; speedup 1.0000x reference)
//
#include <hip/hip_runtime.h>
#include <hip/hip_bf16.h>

// RelationAttn: out = softmax_causal((enc @ R) @ enc^T) @ enc
// enc: [8,2048,1024] f32, R: [1024,1024] f32, out: [8,2048,1024] f32
//
// Kernel 1: Q = enc @ R  (bf16 MFMA, f32 acc), Q stored f32 in d_out.
// Kernel 2: causal flash attention, QB=32 rows/block, KVB=32.
//   Each block: 8 waves. Waves 0-3 compute S partials over 256-d slices,
//   reduced via LDS; wave 0 does online softmax; all waves do PV on a
//   128-wide output slice. K tile staged twice in LDS (row-major + transposed),
//   XOR-swizzled for bank-conflict-free ds_read_b128.
//   Safe d_out reuse: block reads only its own Q rows, writes same rows at end.

typedef __attribute__((ext_vector_type(4))) float f32x4;
typedef __attribute__((ext_vector_type(8))) short bf16x8;
typedef __attribute__((ext_vector_type(4))) short short4v;

#define MFMA16(A, B, C) __builtin_amdgcn_mfma_f32_16x16x32_bf16(A, B, C, 0, 0, 0)

__device__ __forceinline__ short f2bf(float x) {
    union { float f; unsigned u; } v; v.f = x;
    unsigned r = v.u + 0x7fffu + ((v.u >> 16) & 1u);  // RNE to bf16
    return (short)(r >> 16);
}

__device__ __forceinline__ short4v cvt4(f32x4 a) {
    short4v r;
    r[0] = f2bf(a[0]); r[1] = f2bf(a[1]); r[2] = f2bf(a[2]); r[3] = f2bf(a[3]);
    return r;
}

// ---------------------------------------------------------------------------
// Kernel 1: Q = enc(16384x1024) @ R(1024x1024), 128x128 tile, 4 waves (2x2 of 64x64)
// ---------------------------------------------------------------------------
__global__ __launch_bounds__(256) void qr_gemm_kernel(
    const float* __restrict__ A, const float* __restrict__ B, float* C)
{
    // swizzled LDS: elem (row, k) at row*64 + ((k*2) ^ (((row>>1)&3)<<4))
    __shared__ __align__(16) char sA[128 * 64];  // A[m][k] bf16, k=0..31
    __shared__ __align__(16) char sB[128 * 64];  // B^T[n][k] bf16
    const int t = threadIdx.x;
    const int w = t >> 6, l = t & 63;
    const int l15 = l & 15, lg = l >> 4;
    const int bm = blockIdx.x * 128;
    const int bn = blockIdx.y * 128;

    f32x4 acc[4][4];
#pragma unroll
    for (int i = 0; i < 4; ++i)
#pragma unroll
        for (int j = 0; j < 4; ++j) acc[i][j] = (f32x4){0.f, 0.f, 0.f, 0.f};

    const int kq = 4 * (t & 7);   // k sub-block 0,4,...,28
    const int i2 = t >> 3;        // 0..31

    for (int kk = 0; kk < 1024; kk += 32) {
        // stage A: 128 rows x 32 k
#pragma unroll
        for (int it = 0; it < 4; ++it) {
            int m = i2 + 32 * it;
            f32x4 x = *reinterpret_cast<const f32x4*>(&A[(size_t)(bm + m) * 1024 + kk + kq]);
            *reinterpret_cast<short4v*>(sA + m * 64 + ((2 * kq) ^ (((m >> 1) & 3) << 4))) = cvt4(x);
        }
        // stage B transposed: sB[n][k] = R[kk+k][bn+n]
        {
            int n0 = 4 * i2;
            f32x4 x[4];
#pragma unroll
            for (int r = 0; r < 4; ++r)
                x[r] = *reinterpret_cast<const f32x4*>(&B[(size_t)(kk + kq + r) * 1024 + bn + n0]);
#pragma unroll
            for (int j = 0; j < 4; ++j) {
                int n = n0 + j;
                short4v s;
                s[0] = f2bf(x[0][j]); s[1] = f2bf(x[1][j]); s[2] = f2bf(x[2][j]); s[3] = f2bf(x[3][j]);
                *reinterpret_cast<short4v*>(sB + n * 64 + ((2 * kq) ^ (((n >> 1) & 3) << 4))) = s;
            }
        }
        __syncthreads();
        const int r0 = (w >> 1) * 64, c0 = (w & 1) * 64;
        bf16x8 af[4], bfv[4];
#pragma unroll
        for (int mt = 0; mt < 4; ++mt) {
            int m = r0 + 16 * mt + l15;
            af[mt] = *reinterpret_cast<bf16x8*>(sA + m * 64 + ((16 * lg) ^ (((m >> 1) & 3) << 4)));
        }
#pragma unroll
        for (int nt = 0; nt < 4; ++nt) {
            int n = c0 + 16 * nt + l15;
            bfv[nt] = *reinterpret_cast<bf16x8*>(sB + n * 64 + ((16 * lg) ^ (((n >> 1) & 3) << 4)));
        }
#pragma unroll
        for (int mt = 0; mt < 4; ++mt)
#pragma unroll
            for (int nt = 0; nt < 4; ++nt)
                acc[mt][nt] = MFMA16(af[mt], bfv[nt], acc[mt][nt]);
        __syncthreads();
    }
    // C/D layout: col = l&15, row = (l>>4)*4 + reg
#pragma unroll
    for (int mt = 0; mt < 4; ++mt)
#pragma unroll
        for (int nt = 0; nt < 4; ++nt)
#pragma unroll
            for (int rg = 0; rg < 4; ++rg) {
                int row = bm + (w >> 1) * 64 + 16 * mt + 4 * lg + rg;
                int col = bn + (w & 1) * 64 + 16 * nt + l15;
                C[(size_t)row * 1024 + col] = acc[mt][nt][rg];
            }
}

// ---------------------------------------------------------------------------
// Kernel 2: causal flash attention. QB=32 rows/block, KVB=32, 8 waves.
// ---------------------------------------------------------------------------
__global__ __launch_bounds__(512) void attn_kernel(
    const float* __restrict__ enc, float* out /* Q in (from kernel1), O out */)
{
    __shared__ __align__(16) char Kb[32 * 2048];     // K[kv][d] bf16 swz: kv*2048 + ((2d)^((kv&7)<<4))
    __shared__ __align__(16) char Vb[1024 * 64];     // V^T[d][kv] bf16 swz: d*64 + ((2kv)^(((d>>1)&3)<<4))
    __shared__ __align__(16) char Sp[4 * 32 * 128];  // 4 partial S bufs [32][32] f32 swz
    __shared__ __align__(16) char Pb[32 * 64];       // P[32][32] bf16 swz
    __shared__ float Avec[32];                       // per-row rescale factor
    __shared__ float Linv[32];                       // per-row 1/sumexp

    const int t = threadIdx.x;
    const int w = t >> 6, l = t & 63;
    const int l15 = l & 15, lg = l >> 4;     // lg: 0..3
    const int qt = 63 - (int)blockIdx.x;     // descending: heavy blocks first
    const int b = blockIdx.y;
    const int q0 = qt * 32;
    const size_t bofs = (size_t)b * 2048;

    // ---- load Q fragments (waves 0..3 own d-slice [256w, 256w+256)) ----
    bf16x8 qreg[2][8];
    if (w < 4) {
#pragma unroll
        for (int mt = 0; mt < 2; ++mt)
#pragma unroll
            for (int ks = 0; ks < 8; ++ks) {
                const float* src = &out[(bofs + q0 + 16 * mt + l15) * 1024 + 256 * w + 32 * ks + 8 * lg];
                f32x4 x0 = *reinterpret_cast<const f32x4*>(src);
                f32x4 x1 = *reinterpret_cast<const f32x4*>(src + 4);
                bf16x8 q;
                q[0] = f2bf(x0[0]); q[1] = f2bf(x0[1]); q[2] = f2bf(x0[2]); q[3] = f2bf(x0[3]);
                q[4] = f2bf(x1[0]); q[5] = f2bf(x1[1]); q[6] = f2bf(x1[2]); q[7] = f2bf(x1[3]);
                qreg[mt][ks] = q;
            }
    }

    f32x4 accO[2][8];
#pragma unroll
    for (int mt = 0; mt < 2; ++mt)
#pragma unroll
        for (int nt = 0; nt < 8; ++nt) accO[mt][nt] = (f32x4){0.f, 0.f, 0.f, 0.f};

    float m_run = -INFINITY, l_run = 0.f;  // valid in wave 0 (row l&31)

    const int skv = 4 * (t & 7);   // staged kv rows skv..skv+3
    const int sd = 4 * (t >> 3);   // staged d block base

    for (int kvt = 0; kvt <= qt; ++kvt) {
        const int kv0 = kvt * 32;
        __syncthreads();  // B0: previous tile's readers done before restaging
        // ---- stage K tile: dual layout, f32 -> bf16 ----
#pragma unroll
        for (int it = 0; it < 4; ++it) {
            int d0 = sd + 256 * it;
            short4v km[4];
#pragma unroll
            for (int r = 0; r < 4; ++r) {
                f32x4 x = *reinterpret_cast<const f32x4*>(&enc[(bofs + kv0 + skv + r) * 1024 + d0]);
                short4v s = cvt4(x);
                *reinterpret_cast<short4v*>(Kb + (skv + r) * 2048 + ((2 * d0) ^ (((skv + r) & 7) << 4))) = s;
                km[r] = s;
            }
#pragma unroll
            for (int j = 0; j < 4; ++j) {
                int d = d0 + j;
                short4v s;
                s[0] = km[0][j]; s[1] = km[1][j]; s[2] = km[2][j]; s[3] = km[3][j];
                *reinterpret_cast<short4v*>(Vb + d * 64 + ((2 * skv) ^ (((d >> 1) & 3) << 4))) = s;
            }
        }
        __syncthreads();  // B1: staging visible
        // ---- S phase: waves 0..3, S_partial[32q][32kv] over d-slice 256w ----
        if (w < 4) {
            f32x4 accS[2][2];
#pragma unroll
            for (int i = 0; i < 2; ++i)
#pragma unroll
                for (int j = 0; j < 2; ++j) accS[i][j] = (f32x4){0.f, 0.f, 0.f, 0.f};
#pragma unroll
            for (int ks = 0; ks < 8; ++ks) {
                int dd2 = 2 * (256 * w + 32 * ks + 8 * lg);
                bf16x8 k0 = *reinterpret_cast<bf16x8*>(Kb + l15 * 2048 + (dd2 ^ ((l15 & 7) << 4)));
                bf16x8 k1 = *reinterpret_cast<bf16x8*>(Kb + (l15 + 16) * 2048 + (dd2 ^ (((l15 + 16) & 7) << 4)));
                accS[0][0] = MFMA16(qreg[0][ks], k0, accS[0][0]);
                accS[0][1] = MFMA16(qreg[0][ks], k1, accS[0][1]);
                accS[1][0] = MFMA16(qreg[1][ks], k0, accS[1][0]);
                accS[1][1] = MFMA16(qreg[1][ks], k1, accS[1][1]);
            }
#pragma unroll
            for (int mt = 0; mt < 2; ++mt)
#pragma unroll
                for (int nt = 0; nt < 2; ++nt)
#pragma unroll
                    for (int rg = 0; rg < 4; ++rg) {
                        int rr = 16 * mt + 4 * lg + rg;
                        int cc = 16 * nt + l15;
                        *reinterpret_cast<float*>(Sp + w * 4096 + rr * 128 + ((4 * cc) ^ ((rr & 7) << 4))) =
                            accS[mt][nt][rg];
                    }
        }
        __syncthreads();  // B2: partials visible
        // ---- online softmax: wave 0 only (lane: row = l&31, col half h = l>>5) ----
        if (w == 0) {
            const int r = l & 31, h = l >> 5;
            float sv[16];
#pragma unroll
            for (int g = 0; g < 2; ++g) {
                int c0 = 8 * h + 16 * g;
                f32x4 a0 = (f32x4){0.f, 0.f, 0.f, 0.f}, a1 = (f32x4){0.f, 0.f, 0.f, 0.f};
#pragma unroll
                for (int p = 0; p < 4; ++p) {
                    a0 += *reinterpret_cast<f32x4*>(Sp + p * 4096 + r * 128 + ((4 * c0) ^ ((r & 7) << 4)));
                    a1 += *reinterpret_cast<f32x4*>(Sp + p * 4096 + r * 128 + ((4 * (c0 + 4)) ^ ((r & 7) << 4)));
                }
#pragma unroll
                for (int j = 0; j < 4; ++j) { sv[8 * g + j] = a0[j]; sv[8 * g + 4 + j] = a1[j]; }
            }
            if (kvt == qt) {  // causal mask on diagonal tile
#pragma unroll
                for (int g = 0; g < 2; ++g)
#pragma unroll
                    for (int j = 0; j < 8; ++j)
                        if (8 * h + 16 * g + j > r) sv[8 * g + j] = -1e30f;
            }
            float mx = sv[0];
#pragma unroll
            for (int j = 1; j < 16; ++j) mx = fmaxf(mx, sv[j]);
            mx = fmaxf(mx, __shfl_xor(mx, 32));
            float mnew = fmaxf(m_run, mx);
            float alpha = __expf(m_run - mnew);  // 0 on first tile
            float ts = 0.f;
#pragma unroll
            for (int j = 0; j < 16; ++j) {
                float e = __expf(sv[j] - mnew);
                sv[j] = e;
                ts += e;
            }
            ts += __shfl_xor(ts, 32);
            l_run = l_run * alpha + ts;
            m_run = mnew;
            if (l < 32) Avec[l] = alpha;
#pragma unroll
            for (int g = 0; g < 2; ++g) {
                int c0 = 8 * h + 16 * g;
                bf16x8 pv;
#pragma unroll
                for (int j = 0; j < 8; ++j) pv[j] = f2bf(sv[8 * g + j]);
                *reinterpret_cast<bf16x8*>(Pb + r * 64 + ((2 * c0) ^ (((r >> 1) & 3) << 4))) = pv;
            }
        }
        __syncthreads();  // B3: P + alpha visible
        // ---- rescale O and accumulate PV (all 8 waves, O slice d=[128w,128w+128)) ----
        float af_[2][4];
#pragma unroll
        for (int mt = 0; mt < 2; ++mt)
#pragma unroll
            for (int rg = 0; rg < 4; ++rg) af_[mt][rg] = Avec[16 * mt + 4 * lg + rg];
#pragma unroll
        for (int mt = 0; mt < 2; ++mt)
#pragma unroll
            for (int nt = 0; nt < 8; ++nt)
#pragma unroll
                for (int rg = 0; rg < 4; ++rg) accO[mt][nt][rg] *= af_[mt][rg];
        bf16x8 pa[2];
        pa[0] = *reinterpret_cast<bf16x8*>(Pb + l15 * 64 + ((16 * lg) ^ (((l15 >> 1) & 3) << 4)));
        pa[1] = *reinterpret_cast<bf16x8*>(Pb + (l15 + 16) * 64 + ((16 * lg) ^ ((((l15 + 16) >> 1) & 3) << 4)));
#pragma unroll
        for (int nt = 0; nt < 8; ++nt) {
            int dc = 128 * w + 16 * nt + l15;
            bf16x8 vf = *reinterpret_cast<bf16x8*>(Vb + dc * 64 + ((16 * lg) ^ (((dc >> 1) & 3) << 4)));
            accO[0][nt] = MFMA16(pa[0], vf, accO[0][nt]);
            accO[1][nt] = MFMA16(pa[1], vf, accO[1][nt]);
        }
    }

    // ---- finalize: divide by sumexp, write O over Q rows ----
    if (w == 0 && l < 32) Linv[l] = 1.0f / l_run;
    __syncthreads();
    float dv[2][4];
#pragma unroll
    for (int mt = 0; mt < 2; ++mt)
#pragma unroll
        for (int rg = 0; rg < 4; ++rg) dv[mt][rg] = Linv[16 * mt + 4 * lg + rg];
#pragma unroll
    for (int mt = 0; mt < 2; ++mt)
#pragma unroll
        for (int nt = 0; nt < 8; ++nt)
#pragma unroll
            for (int rg = 0; rg < 4; ++rg) {
                size_t row = bofs + q0 + 16 * mt + 4 * lg + rg;
                int col = 128 * w + 16 * nt + l15;
                out[row * 1024 + col] = accO[mt][nt][rg] * dv[mt][rg];
            }
}

// ---------------------------------------------------------------------------
extern "C" void kernel_launch(void* const* d_in, const int* in_sizes, int n_in,
                              void* d_out, int out_size, void* d_ws, size_t ws_size,
                              hipStream_t stream)
{
    const float* enc = (const float*)d_in[0];  // [8,2048,1024]
    const float* R = (const float*)d_in[1];    // [1024,1024]
    float* out = (float*)d_out;                // [8,2048,1024]

    // Q = enc @ R -> d_out (f32). 16384x1024 @ 1024x1024.
    qr_gemm_kernel<<<dim3(128, 8), 256, 0, stream>>>(enc, R, out);
    // causal attention; reads Q from d_out, overwrites with O (row-disjoint per block).
    attn_kernel<<<dim3(64, 8), 512, 0, stream>>>(enc, out);
}